// Round 10
// baseline (157.871 us; speedup 1.0000x reference)
//
#include <hip/hip_runtime.h>
#include <hip/hip_fp16.h>

#define D 32          // MOTIF_DIM
#define H 64          // HIDDEN

typedef __attribute__((ext_vector_type(8))) _Float16 f16x8;
typedef __attribute__((ext_vector_type(4))) float f32x4;

union AB { uint4 u; f16x8 v; __half2 h2[4]; };

// DPP 16-lane row reduction (rows of 16 = our q-groups). All VALU, no DS.
// (proven in R9)
template <int CTRL>
__device__ __forceinline__ float dppadd(float x) {
  int s = __builtin_amdgcn_update_dpp(0, __float_as_int(x), CTRL, 0xF, 0xF, true);
  return x + __int_as_float(s);
}
__device__ __forceinline__ float row16_sum(float x) {
  x = dppadd<0xB1>(x);    // quad_perm [1,0,3,2]  : lane ^ 1
  x = dppadd<0x4E>(x);    // quad_perm [2,3,0,1]  : lane ^ 2
  x = dppadd<0x141>(x);   // row_half_mirror
  x = dppadd<0x140>(x);   // row_mirror
  return x;
}

// ---------------------------------------------------------------------------
// Prep: convert x fp32 -> fp16 rows (RNE). 64 B per node row.
// ---------------------------------------------------------------------------
__global__ __launch_bounds__(256) void pack_x(
    const float* __restrict__ x, unsigned short* __restrict__ xh, int n4) {
  int t = blockIdx.x * 256 + threadIdx.x;
  if (t >= n4) return;
  float4 v = ((const float4*)x)[t];
  ushort4 o;
  o.x = __half_as_ushort(__float2half(v.x));
  o.y = __half_as_ushort(__float2half(v.y));
  o.z = __half_as_ushort(__float2half(v.z));
  o.w = __half_as_ushort(__float2half(v.w));
  ((ushort4*)xh)[t] = o;
}

// ---------------------------------------------------------------------------
// Compute one 16-edge tile. A-frags: mu,mv gathered fp16; c=|mu-mv|, p=mu*mv
// via packed-fp16 VALU (3 ops/dword). B-frags read from LDS right before each
// MFMA (frag f at lane-base + f*1KB). Bias as MFMA C-input; fused layer-2,
// DPP row-reduce, sigmoid, guarded write.
// ---------------------------------------------------------------------------
__device__ __forceinline__ void compute_tile(
    uint4 muU, uint4 mvU, const _Float16* __restrict__ bl,
    const float* __restrict__ b1v, const float* __restrict__ w2v, float bias2,
    int tile, int q, int m, int nE, float* __restrict__ out) {
  AB mu, mv, ac, ap;
  mu.u = muU; mv.u = mvU;
#pragma unroll
  for (int k = 0; k < 4; ++k) {
    ac.h2[k] = __habs2(__hsub2(mu.h2[k], mv.h2[k]));   // v_pk_add_f16(neg)+and
    ap.h2[k] = __hmul2(mu.h2[k], mv.h2[k]);            // v_pk_mul_f16
  }

  float part[4];
#pragma unroll
  for (int t = 0; t < 4; ++t) {
    float bv = b1v[t];
    f32x4 acc = (f32x4){bv, bv, bv, bv};               // bias as MFMA C-input
    acc = __builtin_amdgcn_mfma_f32_16x16x32_f16(
        mu.v, *(const f16x8*)(bl + (t * 4 + 0) * 512), acc, 0, 0, 0);
    acc = __builtin_amdgcn_mfma_f32_16x16x32_f16(
        mv.v, *(const f16x8*)(bl + (t * 4 + 1) * 512), acc, 0, 0, 0);
    acc = __builtin_amdgcn_mfma_f32_16x16x32_f16(
        ac.v, *(const f16x8*)(bl + (t * 4 + 2) * 512), acc, 0, 0, 0);
    acc = __builtin_amdgcn_mfma_f32_16x16x32_f16(
        ap.v, *(const f16x8*)(bl + (t * 4 + 3) * 512), acc, 0, 0, 0);
#pragma unroll
    for (int r = 0; r < 4; ++r) {
      float h = fmaxf(acc[r], 0.f);
      part[r] = (t == 0) ? h * w2v[0] : fmaf(h, w2v[t], part[r]);
    }
  }

#pragma unroll
  for (int r = 0; r < 4; ++r) part[r] = row16_sum(part[r]);

  if (m < 4) {
    int ew = tile * 16 + q * 4 + m;    // overflow tiles -> ew >= nE -> no write
    if (ew < nE) {
      float z = (m == 0 ? part[0] : m == 1 ? part[1] : m == 2 ? part[2] : part[3])
                + bias2;
      out[ew] = 1.f / (1.f + __expf(-z));   // sigmoid in (0,1): clip is no-op
    }
  }
}

// ---------------------------------------------------------------------------
// Main: ONE 16-edge tile per wave iteration (grid-stride), minimal live
// registers so many waves stay resident (TLP > ILP). Prefetch pipeline:
// idx(t+2nW) and gathers(t+nW) issued while computing t. B-fragment table
// (16 frags x 64 lanes x 8 fp16 = 16 KB) built in LDS per block directly
// from W1. Opaque LDS offset stops LICM from hoisting B back to registers.
// ---------------------------------------------------------------------------
__global__ __launch_bounds__(256) void edge_mfma(
    const unsigned short* __restrict__ xh, const float* __restrict__ W1,
    const int* __restrict__ ei,
    const float* __restrict__ b1, const float* __restrict__ W2,
    const float* __restrict__ b2, float* __restrict__ out,
    int nE, int nTiles) {
  __shared__ _Float16 lds_b[16 * 64 * 8];   // 16 KB

  // build B table: frag f = t*4+s, lane l, elem j <- W1[s*32+(l>>4)*8+j][t*16+(l&15)]
#pragma unroll
  for (int i = 0; i < 32; ++i) {
    int id = threadIdx.x + i * 256;          // 0..8191
    int j = id & 7;
    int l = (id >> 3) & 63;
    int f = id >> 9;
    int s = f & 3, t = f >> 2;
    int k = s * 32 + (l >> 4) * 8 + j;
    int n = t * 16 + (l & 15);
    lds_b[id] = (_Float16)W1[k * H + n];
  }
  __syncthreads();

  int lane = threadIdx.x & 63;
  int wid  = (blockIdx.x * 256 + threadIdx.x) >> 6;
  int nW   = (gridDim.x * 256) >> 6;
  int m = lane & 15;        // edge-in-tile (A rows) / hidden-in-tile (C cols)
  int q = lane >> 4;        // quad
  if (wid >= nTiles) return;

  float b1v[4], w2v[4];
#pragma unroll
  for (int t = 0; t < 4; ++t) {
    b1v[t] = b1[t * 16 + m];
    w2v[t] = W2[t * 16 + m];
  }
  float bias2 = b2[0];

  const uint4* xb = (const uint4*)xh;    // node row = 4 uint4; lane reads row*4+q
  int eLim = nE - 1;
  int tLim = nTiles - 1;
  int selOff = (lane & 16) ? nE : 0;     // lanes 0-15 src, 16-31 dst (32-63 dup)
  int eoff = lane & 15;

  // ---- prologue: idx(t0) -> gather(t0); idx(t1) in flight ----
  int t0 = wid;
  int idxNxt;
  uint4 amu, amv;
  {
    int e = t0 * 16 + eoff; e = e < nE ? e : eLim;
    int idxCur = ei[selOff + e];
    int sn = __shfl(idxCur, m);
    int dn = __shfl(idxCur, 16 + m);
    amu = xb[sn * 4 + q];
    amv = xb[dn * 4 + q];
    int t1 = t0 + nW; t1 = t1 < nTiles ? t1 : tLim;
    int e1 = t1 * 16 + eoff; e1 = e1 < nE ? e1 : eLim;
    idxNxt = ei[selOff + e1];
  }

  const _Float16* bl0 = lds_b + lane * 8;

  while (t0 < nTiles) {
    int tn = t0 + nW;
    // distribute next tile's ids, issue its gathers
    int sn = __shfl(idxNxt, m);
    int dn = __shfl(idxNxt, 16 + m);
    uint4 bmu = xb[sn * 4 + q];
    uint4 bmv = xb[dn * 4 + q];
    // issue idx load for t + 2nW (consumed next iteration)
    {
      int t2 = tn + nW; t2 = t2 < nTiles ? t2 : tLim;
      int e2 = t2 * 16 + eoff; e2 = e2 < nE ? e2 : eLim;
      idxNxt = ei[selOff + e2];
    }

    // opaque LDS base: stop LICM from hoisting B-frag LDS loads to registers
    const _Float16* bl = bl0;
    asm volatile("" : "+v"(bl));

    compute_tile(amu, amv, bl, b1v, w2v, bias2, t0, q, m, nE, out);

    amu = bmu; amv = bmv;
    t0 = tn;
  }
}

// ---------------------------------------------------------------------------
// Fallback (ws too small): all-fp32 per edge, no workspace needed.
// ---------------------------------------------------------------------------
__global__ __launch_bounds__(256) void edge_full(
    const float* __restrict__ x, const int* __restrict__ ei,
    const float* __restrict__ W1, const float* __restrict__ b1,
    const float* __restrict__ W2, const float* __restrict__ b2,
    float* __restrict__ out, int nE) {
  int e = blockIdx.x * 256 + threadIdx.x;
  if (e >= nE) return;
  int s = ei[e];
  int d = ei[e + nE];
  const float4* mu4 = (const float4*)(x + (size_t)s * D);
  const float4* mv4 = (const float4*)(x + (size_t)d * D);
  float mu[D], mv[D], c[D], p[D];
#pragma unroll
  for (int qq = 0; qq < D / 4; ++qq) {
    float4 a = mu4[qq];
    float4 b = mv4[qq];
    mu[4*qq+0] = a.x; mv[4*qq+0] = b.x; c[4*qq+0] = fabsf(a.x-b.x); p[4*qq+0] = a.x*b.x;
    mu[4*qq+1] = a.y; mv[4*qq+1] = b.y; c[4*qq+1] = fabsf(a.y-b.y); p[4*qq+1] = a.y*b.y;
    mu[4*qq+2] = a.z; mv[4*qq+2] = b.z; c[4*qq+2] = fabsf(a.z-b.z); p[4*qq+2] = a.z*b.z;
    mu[4*qq+3] = a.w; mv[4*qq+3] = b.w; c[4*qq+3] = fabsf(a.w-b.w); p[4*qq+3] = a.w*b.w;
  }
  float z = b2[0];
  for (int j = 0; j < H; ++j) {
    float a = b1[j];
#pragma unroll
    for (int k = 0; k < D; ++k) {
      a = fmaf(mu[k], W1[k * H + j], a);
      a = fmaf(mv[k], W1[(D + k) * H + j], a);
      a = fmaf(c[k],  W1[(2 * D + k) * H + j], a);
      a = fmaf(p[k],  W1[(3 * D + k) * H + j], a);
    }
    a = fmaxf(a, 0.f);
    z = fmaf(a, W2[j], z);
  }
  float g = 1.f / (1.f + __expf(-z));
  out[e] = fminf(fmaxf(g, 0.f), 1.f);
}

extern "C" void kernel_launch(void* const* d_in, const int* in_sizes, int n_in,
                              void* d_out, int out_size, void* d_ws, size_t ws_size,
                              hipStream_t stream) {
  const float* x  = (const float*)d_in[0];
  const int*   ei = (const int*)d_in[1];
  const float* W1 = (const float*)d_in[2];
  const float* b1 = (const float*)d_in[3];
  const float* W2 = (const float*)d_in[4];
  const float* b2 = (const float*)d_in[5];
  float* out = (float*)d_out;

  int nN = in_sizes[0] / D;      // 100000
  int nE = in_sizes[1] / 2;      // 1600000

  size_t need = (size_t)nN * D * sizeof(unsigned short);  // 6.4 MB
  if (ws_size >= need) {
    unsigned short* xh = (unsigned short*)d_ws;
    int n4 = nN * D / 4;
    pack_x<<<(n4 + 255) / 256, 256, 0, stream>>>(x, xh, n4);
    int nTiles = (nE + 15) / 16;
    edge_mfma<<<2048, 256, 0, stream>>>(xh, W1, ei, b1, W2, b2, out, nE, nTiles);
  } else {
    edge_full<<<(nE + 255) / 256, 256, 0, stream>>>(x, ei, W1, b1, W2, b2, out, nE);
  }
}